// Round 12
// baseline (299.993 us; speedup 1.0000x reference)
//
#include <hip/hip_runtime.h>

static constexpr int TPB = 256;
static constexpr int SD = 21, HD = 64, LT = 14;

// dot2 packed weights (R8 layout, u32 = 2xf16 along K)
static constexpr int P1_OFF = 0, P2_OFF = 704, P3_OFF = 2752, PD1_OFF = 3200,
                     PD2_OFF = 3648, PTOT = 3904;
// enc2 B-fragments for the MFMA test (u32 offset in ws)
static constexpr int FRAG_BASE = 4096;
static constexpr int NFRAG2 = 16;

typedef _Float16       h2_t   __attribute__((ext_vector_type(2)));
typedef _Float16       f16x4  __attribute__((ext_vector_type(4)));
typedef float          f32x4  __attribute__((ext_vector_type(4)));
typedef unsigned       u32x2v __attribute__((ext_vector_type(2)));
typedef unsigned short u16x4v __attribute__((ext_vector_type(4)));
typedef __fp16         pk2    __attribute__((ext_vector_type(2)));

__device__ __forceinline__ float frcp(float x){ return __builtin_amdgcn_rcpf(x); }
__device__ __forceinline__ float frsq(float x){ return __builtin_amdgcn_rsqf(x); }

__device__ __forceinline__ unsigned packrtz(float a, float b){
    pk2 h = __builtin_amdgcn_cvt_pkrtz(a, b);
    union { pk2 h; unsigned u; } u; u.h = h; return u.u;
}
__device__ __forceinline__ float dot2(unsigned xp, unsigned wp, float acc){
    union { unsigned u; h2_t h; } a, b; a.u = xp; b.u = wp;
    return __builtin_amdgcn_fdot2(a.h, b.h, acc, false);
}
__device__ __forceinline__ float ftanh(float x){
    x = fminf(15.0f, fmaxf(-15.0f, x));
    float e = __expf(2.0f * x);
    return (e - 1.0f) * frcp(e + 1.0f);
}
template<int NN>
__device__ __forceinline__ void softmax_scale(float (&v)[NN], float gate){
    float mx = v[0];
#pragma unroll
    for (int j = 1; j < NN; ++j) mx = fmaxf(mx, v[j]);
    float s = 0.0f;
#pragma unroll
    for (int j = 0; j < NN; ++j){ v[j] = __expf(v[j] - mx); s += v[j]; }
    float r = frcp(s) * gate;
#pragma unroll
    for (int j = 0; j < NN; ++j) v[j] *= r;
}

union Frag2 { u32x2v u2; unsigned u[2]; f16x4 f; };
union FragH { u16x4v uh; f16x4 f; };

__device__ __forceinline__ f32x4 mfma16(f16x4 a, f16x4 b, f32x4 c){
    return __builtin_amdgcn_mfma_f32_16x16x16f16(a, b, c, 0, 0, 0);
}

// read f16 element [row][col] from a [32][36]-u32 pair buffer
__device__ __forceinline__ float gt_at(const unsigned* gtb, int row, int col){
    unsigned u = gtb[row*36 + (col >> 1)];
    unsigned short s = (col & 1) ? (unsigned short)(u >> 16) : (unsigned short)(u & 0xffff);
    union { unsigned short s; _Float16 h; } c; c.s = s;
    return (float)c.h;
}

// ---- R8's dot2 weight pack ----
__global__ void pack_weights_kernel(const float* __restrict__ W1, const float* __restrict__ W2,
                                    const float* __restrict__ W3, const float* __restrict__ Wd1,
                                    const float* __restrict__ Wd2, unsigned* __restrict__ ws)
{
    int idx = blockIdx.x * blockDim.x + threadIdx.x;
    if (idx >= PTOT) return;
    float a, b;
    if (idx < P2_OFF) {
        int e = idx - P1_OFF, kk = e >> 6, j = e & 63;
        a = W1[(2*kk)*HD + j];
        b = (2*kk + 1 < SD) ? W1[(2*kk+1)*HD + j] : 0.0f;
    } else if (idx < P3_OFF) {
        int e = idx - P2_OFF, kk = e >> 6, j = e & 63;
        a = W2[(2*kk)*HD + j];  b = W2[(2*kk+1)*HD + j];
    } else if (idx < PD1_OFF) {
        int e = idx - P3_OFF, kk = e / LT, j = e % LT;
        a = W3[(2*kk)*LT + j];  b = W3[(2*kk+1)*LT + j];
    } else if (idx < PD2_OFF) {
        int e = idx - PD1_OFF, kk = e >> 6, j = e & 63;
        a = Wd1[(2*kk)*HD + j]; b = Wd1[(2*kk+1)*HD + j];
    } else {
        int e = idx - PD2_OFF, kk = e >> 3, j = e & 7;
        a = Wd2[(2*kk)*8 + j];  b = Wd2[(2*kk+1)*8 + j];
    }
    ws[idx] = packrtz(a, b);
}

// ---- enc2 B-fragments: assumed layout col=l&15, k=4*(l>>4)+r (+16*ks16) ----
__global__ void pack_bfrags2(const float* __restrict__ W2, unsigned* __restrict__ ws)
{
    int t = blockIdx.x * blockDim.x + threadIdx.x;
    if (t >= NFRAG2 * 64) return;
    int fid = t >> 6, lane = t & 63, g = lane >> 4, c = lane & 15;
    int ks16 = fid >> 2, ct = fid & 3, col = ct*16 + c;
#pragma unroll
    for (int j = 0; j < 2; ++j) {
        int k0 = ks16*16 + g*4 + 2*j;
        ws[FRAG_BASE + fid*128 + lane*2 + j] = packrtz(W2[k0*HD + col], W2[(k0+1)*HD + col]);
    }
}

__global__ __launch_bounds__(TPB, 4) void statenet_hybrid(
    const float* __restrict__ state,
    const unsigned* __restrict__ pw,
    const float* __restrict__ b1,
    const float* __restrict__ lng, const float* __restrict__ lnb,
    const float* __restrict__ b2,  const float* __restrict__ b3,
    const float* __restrict__ bd1, const float* __restrict__ bd2,
    const float* __restrict__ Wm,  const float* __restrict__ bm,
    const float* __restrict__ Wh,  const float* __restrict__ bh,
    const float* __restrict__ Wc,  const float* __restrict__ bc,
    const float* __restrict__ psm, const float* __restrict__ psh,
    const float* __restrict__ psc,
    float* __restrict__ out, int N)
{
    __shared__ __align__(16) unsigned s_hb[4*1152];  // per wave: rows 0..31 of h (f16 pairs, [32][36])
    __shared__ __align__(16) unsigned s_gt[4*1152];  // per wave: dot2 ground-truth h2 (f16 pairs)
    __shared__ int s_flag[4];

    const int tid = threadIdx.x;
    const int w = tid >> 6, l = tid & 63, cl = l & 15, g = l >> 4;
    const long long row = (long long)blockIdx.x * TPB + tid;

    unsigned* hb  = s_hb + w*1152;
    unsigned* gtb = s_gt + w*1152;

    // =================== R8 dot2 path (proven) ===================
    float ns[SD];
    {
        const float* p = state + row * SD;
#pragma unroll
        for (int k = 0; k < SD; ++k) ns[k] = p[k];
    }
    ns[0]  *= (1.0f / 3.0f);
    ns[1]  *= (1.0f / 3.0f);
    ns[17] *= 0.5f;
    ns[18] *= 0.25f;
    ns[19]  = fminf(fmaxf(ns[19], 0.0f), 2.0f) * 0.5f;

    float m[13], hv[6], cv[4];
#pragma unroll
    for (int j = 0; j < 13; ++j) m[j]  = bm[j];
#pragma unroll
    for (int j = 0; j < 6;  ++j) hv[j] = bh[j];
#pragma unroll
    for (int j = 0; j < 4;  ++j) cv[j] = bc[j];
#pragma unroll
    for (int k = 0; k < SD; ++k) {
        float x = ns[k];
#pragma unroll
        for (int j = 0; j < 13; ++j) m[j]  = fmaf(x, Wm[k * 13 + j], m[j]);
#pragma unroll
        for (int j = 0; j < 6;  ++j) hv[j] = fmaf(x, Wh[k * 6 + j], hv[j]);
#pragma unroll
        for (int j = 0; j < 4;  ++j) cv[j] = fmaf(x, Wc[k * 4 + j], cv[j]);
    }
    const float gm = 2.0f * frcp(1.0f + __expf(-psm[0]));
    const float gh = 2.0f * frcp(1.0f + __expf(-psh[0]));
    const float gc = 2.0f * frcp(1.0f + __expf(-psc[0]));
    softmax_scale<13>(m,  gm);
    softmax_scale<6 >(hv, gh);
    softmax_scale<4 >(cv, gc);

    {
        float* pm = out + (long long)22 * N + row * 13;
#pragma unroll
        for (int j = 0; j < 13; ++j) pm[j] = m[j];
        float* ph = out + (long long)35 * N + row * 6;
#pragma unroll
        for (int j = 0; j < 3; ++j)
            reinterpret_cast<float2*>(ph)[j] = make_float2(hv[2*j], hv[2*j+1]);
        float* pc = out + (long long)41 * N + row * 4;
        reinterpret_cast<float4*>(pc)[0] = make_float4(cv[0], cv[1], cv[2], cv[3]);
    }

    constexpr int EIDX[SD] = {0,1,2,3,4,4,5,5,5,6,6,6,7,7,8,9,9,10,10,11,12};
    float at[SD];
#pragma unroll
    for (int k = 0; k < SD; ++k) at[k] = ns[k] * m[EIDX[k]];
    unsigned atp[11];
#pragma unroll
    for (int kk = 0; kk < 10; ++kk) atp[kk] = packrtz(at[2*kk], at[2*kk+1]);
    atp[10] = packrtz(at[20], 0.0f);

    float h[HD];
#pragma unroll
    for (int j = 0; j < HD; ++j) h[j] = b1[j];
#pragma unroll
    for (int kk = 0; kk < 11; ++kk) {
        unsigned x = atp[kk];
        const unsigned* wr = pw + P1_OFF + kk * HD;
#pragma unroll
        for (int j = 0; j < HD; ++j) h[j] = dot2(x, wr[j], h[j]);
    }

    float mu = 0.0f;
#pragma unroll
    for (int j = 0; j < HD; ++j) mu += h[j];
    mu *= (1.0f / HD);
    float var = 0.0f;
#pragma unroll
    for (int j = 0; j < HD; ++j) { float d = h[j] - mu; var = fmaf(d, d, var); }
    var *= (1.0f / HD);
    float istd = frsq(var + 1e-5f);
#pragma unroll
    for (int j = 0; j < HD; ++j)
        h[j] = ftanh(fmaf((h[j] - mu) * istd, lng[j], lnb[j]));

    unsigned hp[32];
#pragma unroll
    for (int kk = 0; kk < 32; ++kk) hp[kk] = packrtz(h[2*kk], h[2*kk+1]);

    // stage A-operand rows 0..31 of this wave for the MFMA test
    if (l < 32) {
#pragma unroll
        for (int kk = 0; kk < 32; ++kk) hb[l*36 + kk] = hp[kk];
    }

    float h2[HD];
#pragma unroll
    for (int j = 0; j < HD; ++j) h2[j] = b2[j];
#pragma unroll
    for (int kk = 0; kk < 32; ++kk) {
        unsigned x = hp[kk];
        const unsigned* wr = pw + P2_OFF + kk * HD;
#pragma unroll
        for (int j = 0; j < HD; ++j) h2[j] = dot2(x, wr[j], h2[j]);
    }
#pragma unroll
    for (int j = 0; j < HD; ++j) h2[j] = fmaxf(h2[j], 0.0f);

    // stage enc2 ground truth (f16 pairs)
    if (l < 32) {
#pragma unroll
        for (int kk = 0; kk < 32; ++kk) gtb[l*36 + kk] = packrtz(h2[2*kk], h2[2*kk+1]);
    }

    unsigned h2p[32];
#pragma unroll
    for (int kk = 0; kk < 32; ++kk) h2p[kk] = packrtz(h2[2*kk], h2[2*kk+1]);

    float lat[LT];
#pragma unroll
    for (int j = 0; j < LT; ++j) lat[j] = b3[j];
#pragma unroll
    for (int kk = 0; kk < 32; ++kk) {
        unsigned x = h2p[kk];
        const unsigned* wr = pw + P3_OFF + kk * LT;
#pragma unroll
        for (int j = 0; j < LT; ++j) lat[j] = dot2(x, wr[j], lat[j]);
    }
    {
        float* pl = out + (long long)8 * N + row * 14;
#pragma unroll
        for (int j = 0; j < 7; ++j)
            reinterpret_cast<float2*>(pl)[j] = make_float2(lat[2*j], lat[2*j+1]);
    }

    unsigned latp[7];
#pragma unroll
    for (int kk = 0; kk < 7; ++kk) latp[kk] = packrtz(lat[2*kk], lat[2*kk+1]);
    float d1[HD];
#pragma unroll
    for (int j = 0; j < HD; ++j) d1[j] = bd1[j];
#pragma unroll
    for (int kk = 0; kk < 7; ++kk) {
        unsigned x = latp[kk];
        const unsigned* wr = pw + PD1_OFF + kk * HD;
#pragma unroll
        for (int j = 0; j < HD; ++j) d1[j] = dot2(x, wr[j], d1[j]);
    }
#pragma unroll
    for (int j = 0; j < HD; ++j) d1[j] = fmaxf(d1[j], 0.0f);

    unsigned d1p[32];
#pragma unroll
    for (int kk = 0; kk < 32; ++kk) d1p[kk] = packrtz(d1[2*kk], d1[2*kk+1]);
    float c8[8];
#pragma unroll
    for (int j = 0; j < 8; ++j) c8[j] = bd2[j];
#pragma unroll
    for (int kk = 0; kk < 32; ++kk) {
        unsigned x = d1p[kk];
        const unsigned* wr = pw + PD2_OFF + kk * 8;
#pragma unroll
        for (int j = 0; j < 8; ++j) c8[j] = dot2(x, wr[j], c8[j]);
    }

    // =================== MFMA diagnostic (enc2, rows 0..31 of this wave) ===================
    __syncthreads();
    int bad1 = 0, bad2 = 0;
    {
        const unsigned short* hb16 = reinterpret_cast<const unsigned short*>(hb);
        const u32x2v* BF2 = reinterpret_cast<const u32x2v*>(pw + FRAG_BASE);
        FragH ah[2][4];
#pragma unroll
        for (int m2 = 0; m2 < 2; ++m2)
#pragma unroll
            for (int ks = 0; ks < 4; ++ks)
                ah[m2][ks].uh = *reinterpret_cast<const u16x4v*>(&hb16[(m2*16 + cl)*72 + ks*16 + 4*g]);
        const f32x4 vzero = {0.0f, 0.0f, 0.0f, 0.0f};
        f32x4 acc[2][4];
#pragma unroll
        for (int m2 = 0; m2 < 2; ++m2)
#pragma unroll
            for (int ct = 0; ct < 4; ++ct) acc[m2][ct] = vzero;
#pragma unroll
        for (int ct = 0; ct < 4; ++ct)
#pragma unroll
            for (int ks = 0; ks < 4; ++ks) {
                Frag2 bf; bf.u2 = BF2[(ks*4 + ct)*64 + l];
#pragma unroll
                for (int m2 = 0; m2 < 2; ++m2)
                    acc[m2][ct] = mfma16(ah[m2][ks].f, bf.f, acc[m2][ct]);
            }
#pragma unroll
        for (int m2 = 0; m2 < 2; ++m2)
#pragma unroll
            for (int ct = 0; ct < 4; ++ct)
#pragma unroll
                for (int q = 0; q < 4; ++q) {
                    // convention 1: row=(l>>4)*4+q, col=l&15 (+tiles)
                    int r1 = m2*16 + g*4 + q, c1 = cl + 16*ct;
                    float v1 = fmaxf(acc[m2][ct][q] + b2[c1], 0.0f);
                    if (fabsf(v1 - gt_at(gtb, r1, c1)) > 0.05f) bad1 = 1;
                    // convention 2 (transposed): row=l&15, col=(l>>4)*4+q
                    int r2 = m2*16 + cl, c2 = ct*16 + g*4 + q;
                    float v2 = fmaxf(acc[m2][ct][q] + b2[c2], 0.0f);
                    if (fabsf(v2 - gt_at(gtb, r2, c2)) > 0.05f) bad2 = 1;
                }
    }
    int a1 = __any(bad1), a2 = __any(bad2);
    if (l == 0) s_flag[w] = (a1 ? 1 : 0) | (a2 ? 2 : 0);
    __syncthreads();
    float poison = 0.0f;
    {
        int f = s_flag[w];
        if (f & 1) poison = (f & 2) ? 3000.0f : 1000.0f;
    }

    {
        float* pc = out + row * 8;
        reinterpret_cast<float4*>(pc)[0] =
            make_float4(ftanh(c8[0]) + poison, ftanh(c8[1]) + poison,
                        ftanh(c8[2]) + poison, ftanh(c8[3]) + poison);
        reinterpret_cast<float4*>(pc)[1] =
            make_float4(ftanh(c8[4]) + poison, ftanh(c8[5]) + poison,
                        ftanh(c8[6]) + poison, ftanh(c8[7]) + poison);
    }
}

extern "C" void kernel_launch(void* const* d_in, const int* in_sizes, int n_in,
                              void* d_out, int out_size, void* d_ws, size_t ws_size,
                              hipStream_t stream)
{
    const float* state = (const float*)d_in[0];
    const float* W1   = (const float*)d_in[1];
    const float* b1   = (const float*)d_in[2];
    const float* lng  = (const float*)d_in[3];
    const float* lnb  = (const float*)d_in[4];
    const float* W2   = (const float*)d_in[5];
    const float* b2   = (const float*)d_in[6];
    const float* W3   = (const float*)d_in[7];
    const float* b3   = (const float*)d_in[8];
    const float* Wd1  = (const float*)d_in[9];
    const float* bd1  = (const float*)d_in[10];
    const float* Wd2  = (const float*)d_in[11];
    const float* bd2  = (const float*)d_in[12];
    const float* Wm   = (const float*)d_in[13];
    const float* bm   = (const float*)d_in[14];
    const float* Wh   = (const float*)d_in[15];
    const float* bh   = (const float*)d_in[16];
    const float* Wc   = (const float*)d_in[17];
    const float* bc   = (const float*)d_in[18];
    const float* psm  = (const float*)d_in[19];
    const float* psh  = (const float*)d_in[20];
    const float* psc  = (const float*)d_in[21];

    unsigned* pw = (unsigned*)d_ws;

    hipLaunchKernelGGL(pack_weights_kernel, dim3((PTOT + 255)/256), dim3(256), 0, stream,
                       W1, W2, W3, Wd1, Wd2, pw);
    hipLaunchKernelGGL(pack_bfrags2, dim3((NFRAG2*64 + 255)/256), dim3(256), 0, stream,
                       W2, pw);

    const int N = in_sizes[0] / SD;              // 1048576
    hipLaunchKernelGGL(statenet_hybrid, dim3((N + TPB - 1)/TPB), dim3(TPB), 0, stream,
                       state, pw, b1, lng, lnb, b2, b3, bd1, bd2,
                       Wm, bm, Wh, bh, Wc, bc, psm, psh, psc,
                       (float*)d_out, N);
}

// Round 15
// 162.396 us; speedup vs baseline: 1.8473x; 1.8473x over previous
//
#include <hip/hip_runtime.h>

static constexpr int SD = 21, HD = 64, LT = 14;
static constexpr int P1_OFF = 0, P2_OFF = 704, P3_OFF = 2752, PD1_OFF = 3200,
                     PD2_OFF = 3648, PTOT = 3904;
static constexpr int FRAG_BASE = 4096;
static constexpr int NFRAG = 36;

typedef _Float16       h2_t   __attribute__((ext_vector_type(2)));
typedef _Float16       f16x4  __attribute__((ext_vector_type(4)));
typedef float          f32x4  __attribute__((ext_vector_type(4)));
typedef unsigned       u32x2v __attribute__((ext_vector_type(2)));
typedef unsigned short u16x4v __attribute__((ext_vector_type(4)));
typedef __fp16         pk2    __attribute__((ext_vector_type(2)));

__device__ __forceinline__ float frcp(float x){ return __builtin_amdgcn_rcpf(x); }
__device__ __forceinline__ float frsq(float x){ return __builtin_amdgcn_rsqf(x); }

__device__ __forceinline__ unsigned packrtz(float a, float b){
    pk2 h = __builtin_amdgcn_cvt_pkrtz(a, b);
    union { pk2 h; unsigned u; } u; u.h = h; return u.u;
}
__device__ __forceinline__ float dot2(unsigned xp, unsigned wp, float acc){
    union { unsigned u; h2_t h; } a, b; a.u = xp; b.u = wp;
    return __builtin_amdgcn_fdot2(a.h, b.h, acc, false);
}
__device__ __forceinline__ unsigned short f16bits(float v){
    _Float16 h = (_Float16)v;
    union { _Float16 h; unsigned short s; } u; u.h = h; return u.s;
}
__device__ __forceinline__ float ftanh(float x){
    x = fminf(15.0f, fmaxf(-15.0f, x));
    float e = __expf(2.0f * x);
    return (e - 1.0f) * frcp(e + 1.0f);
}
template<int NN>
__device__ __forceinline__ void softmax_scale(float (&v)[NN], float gate){
    float mx = v[0];
#pragma unroll
    for (int j = 1; j < NN; ++j) mx = fmaxf(mx, v[j]);
    float s = 0.0f;
#pragma unroll
    for (int j = 0; j < NN; ++j){ v[j] = __expf(v[j] - mx); s += v[j]; }
    float r = frcp(s) * gate;
#pragma unroll
    for (int j = 0; j < NN; ++j) v[j] *= r;
}

union Frag2 { u32x2v u2; unsigned u[2]; f16x4 f; };
union FragH { u16x4v uh; f16x4 f; };

__device__ __forceinline__ f32x4 mfma16(f16x4 a, f16x4 b, f32x4 c){
    return __builtin_amdgcn_mfma_f32_16x16x16f16(a, b, c, 0, 0, 0);
}

__global__ void pack_weights_kernel(const float* __restrict__ W1, const float* __restrict__ W2,
                                    const float* __restrict__ W3, const float* __restrict__ Wd1,
                                    const float* __restrict__ Wd2, unsigned* __restrict__ ws)
{
    int idx = blockIdx.x * blockDim.x + threadIdx.x;
    if (idx >= PTOT) return;
    float a, b;
    if (idx < P2_OFF) {
        int e = idx, kk = e >> 6, j = e & 63;
        a = W1[(2*kk)*HD + j];
        b = (2*kk + 1 < SD) ? W1[(2*kk+1)*HD + j] : 0.0f;
    } else if (idx < P3_OFF) {
        int e = idx - P2_OFF, kk = e >> 6, j = e & 63;
        a = W2[(2*kk)*HD + j];  b = W2[(2*kk+1)*HD + j];
    } else if (idx < PD1_OFF) {
        int e = idx - P3_OFF, kk = e / LT, j = e % LT;
        a = W3[(2*kk)*LT + j];  b = W3[(2*kk+1)*LT + j];
    } else if (idx < PD2_OFF) {
        int e = idx - PD1_OFF, kk = e >> 6, j = e & 63;
        a = Wd1[(2*kk)*HD + j]; b = Wd1[(2*kk+1)*HD + j];
    } else {
        int e = idx - PD2_OFF, kk = e >> 3, j = e & 7;
        a = Wd2[(2*kk)*8 + j];  b = Wd2[(2*kk+1)*8 + j];
    }
    ws[idx] = packrtz(a, b);
}

__global__ void pack_bfrags(const float* __restrict__ W1, const float* __restrict__ W2,
                            const float* __restrict__ W3, const float* __restrict__ Wd1,
                            const float* __restrict__ Wd2, unsigned* __restrict__ ws)
{
    int t = blockIdx.x * blockDim.x + threadIdx.x;
    if (t >= NFRAG * 64) return;
    int fid = t >> 6, lane = t & 63;
    int g = lane >> 4, c = lane & 15;
    const float* W; int ks16, ct, K, Ncol, ld;
    if (fid < 8)       { W = W1;  ks16 = fid >> 2;    ct = fid & 3;  K = 21; Ncol = 64; ld = 64; }
    else if (fid < 24) { int e = fid - 8;
                         W = W2;  ks16 = e >> 2;      ct = e & 3;    K = 64; Ncol = 64; ld = 64; }
    else if (fid < 28) { W = W3;  ks16 = fid - 24;    ct = 0;        K = 64; Ncol = 14; ld = 14; }
    else if (fid < 32) { W = Wd1; ks16 = 0;           ct = fid - 28; K = 14; Ncol = 64; ld = 64; }
    else               { W = Wd2; ks16 = fid - 32;    ct = 0;        K = 64; Ncol = 8;  ld = 8;  }
    int col = ct*16 + c;
#pragma unroll
    for (int j = 0; j < 2; ++j) {
        int k0 = ks16*16 + g*4 + 2*j;
        float a = (k0     < K && col < Ncol) ? W[k0*ld + col]     : 0.0f;
        float b = (k0 + 1 < K && col < Ncol) ? W[(k0+1)*ld + col] : 0.0f;
        ws[FRAG_BASE + fid*128 + lane*2 + j] = packrtz(a, b);
    }
}

__global__ __launch_bounds__(256) void statenet_hybrid2(
    const float* __restrict__ state,
    const unsigned* __restrict__ pw,
    const float* __restrict__ b1,
    const float* __restrict__ lng, const float* __restrict__ lnb,
    const float* __restrict__ b2,  const float* __restrict__ b3,
    const float* __restrict__ bd1, const float* __restrict__ bd2,
    const float* __restrict__ Wm,  const float* __restrict__ bm,
    const float* __restrict__ Wh,  const float* __restrict__ bh,
    const float* __restrict__ Wc,  const float* __restrict__ bc,
    const float* __restrict__ psm, const float* __restrict__ psh,
    const float* __restrict__ psc,
    float* __restrict__ out, int N)
{
    __shared__ __align__(16) unsigned       s_al[4*1152];   // at staging / latent f32 [32][36]/wave
    __shared__ __align__(16) unsigned short s_hb[4*2304];   // h [32][72] f16 /wave

    const int tid = threadIdx.x;
    const int w  = tid >> 6, l = tid & 63;
    const int cl = l & 15,  g = l >> 4;
    const long long rowbase = (long long)blockIdx.x * 128 + w * 32;

    unsigned*       at  = s_al + w * 1152;
    unsigned short* hb  = s_hb + w * 2304;

    // ============ T1: heads + attended staging (lanes 0..31; VERIFIED) ============
    if (l < 32) {
        const long long row = rowbase + l;
        float ns[SD];
        {
            const float* p = state + row * SD;
#pragma unroll
            for (int k = 0; k < SD; ++k) ns[k] = p[k];
        }
        ns[0]  *= (1.0f / 3.0f);
        ns[1]  *= (1.0f / 3.0f);
        ns[17] *= 0.5f;
        ns[18] *= 0.25f;
        ns[19]  = fminf(fmaxf(ns[19], 0.0f), 2.0f) * 0.5f;

        float m[13], hv[6], cv[4];
#pragma unroll
        for (int j = 0; j < 13; ++j) m[j]  = bm[j];
#pragma unroll
        for (int j = 0; j < 6;  ++j) hv[j] = bh[j];
#pragma unroll
        for (int j = 0; j < 4;  ++j) cv[j] = bc[j];
#pragma unroll
        for (int k = 0; k < SD; ++k) {
            float x = ns[k];
#pragma unroll
            for (int j = 0; j < 13; ++j) m[j]  = fmaf(x, Wm[k * 13 + j], m[j]);
#pragma unroll
            for (int j = 0; j < 6;  ++j) hv[j] = fmaf(x, Wh[k * 6 + j], hv[j]);
#pragma unroll
            for (int j = 0; j < 4;  ++j) cv[j] = fmaf(x, Wc[k * 4 + j], cv[j]);
        }
        const float gm = 2.0f * frcp(1.0f + __expf(-psm[0]));
        const float gh = 2.0f * frcp(1.0f + __expf(-psh[0]));
        const float gc = 2.0f * frcp(1.0f + __expf(-psc[0]));
        softmax_scale<13>(m,  gm);
        softmax_scale<6 >(hv, gh);
        softmax_scale<4 >(cv, gc);

        {
            float* pm = out + (long long)22 * N + row * 13;
#pragma unroll
            for (int j = 0; j < 13; ++j) pm[j] = m[j];
            float* ph = out + (long long)35 * N + row * 6;
#pragma unroll
            for (int j = 0; j < 3; ++j)
                reinterpret_cast<float2*>(ph)[j] = make_float2(hv[2*j], hv[2*j+1]);
            float* pc = out + (long long)41 * N + row * 4;
            reinterpret_cast<float4*>(pc)[0] = make_float4(cv[0], cv[1], cv[2], cv[3]);
        }

        constexpr int EIDX[SD] = {0,1,2,3,4,4,5,5,5,6,6,6,7,7,8,9,9,10,10,11,12};
        float atv[SD];
#pragma unroll
        for (int k = 0; k < SD; ++k) atv[k] = ns[k] * m[EIDX[k]];
        const int base = l * 36;
#pragma unroll
        for (int kk = 0; kk < 10; ++kk) at[base + kk] = packrtz(atv[2*kk], atv[2*kk+1]);
        at[base + 10] = packrtz(atv[20], 0.0f);
#pragma unroll
        for (int kk = 11; kk < 16; ++kk) at[base + kk] = 0u;
    }
    __syncthreads();

    // ============ MFMA phase (enc1/enc2/enc3 — all VERIFIED) ============
    float b1c[4], b2c[4], lgc[4], lbc[4];
#pragma unroll
    for (int t2 = 0; t2 < 4; ++t2) {
        int c2 = cl + 16*t2;
        b1c[t2] = b1[c2];  b2c[t2] = b2[c2];
        lgc[t2] = lng[c2]; lbc[t2] = lnb[c2];
    }
    const float b3c = (cl < 14) ? b3[cl] : 0.0f;

    const u32x2v* BF2 = reinterpret_cast<const u32x2v*>(pw + FRAG_BASE);
    const f32x4 vzero = {0.0f, 0.0f, 0.0f, 0.0f};

    // ---- enc1 MFMA + LN + tanh -> hb ----
    Frag2 aA[2][2];
#pragma unroll
    for (int m2 = 0; m2 < 2; ++m2)
#pragma unroll
        for (int ks = 0; ks < 2; ++ks)
            aA[m2][ks].u2 = *reinterpret_cast<const u32x2v*>(&at[(m2*16 + cl)*36 + ks*8 + 2*g]);
    f32x4 acc[2][4];
#pragma unroll
    for (int m2 = 0; m2 < 2; ++m2)
#pragma unroll
        for (int ct = 0; ct < 4; ++ct) acc[m2][ct] = vzero;
#pragma unroll
    for (int ct = 0; ct < 4; ++ct)
#pragma unroll
        for (int ks = 0; ks < 2; ++ks) {
            Frag2 bf; bf.u2 = BF2[(ks*4 + ct)*64 + l];
#pragma unroll
            for (int m2 = 0; m2 < 2; ++m2)
                acc[m2][ct] = mfma16(aA[m2][ks].f, bf.f, acc[m2][ct]);
        }
#pragma unroll
    for (int m2 = 0; m2 < 2; ++m2) {
        float s[4], ss[4];
#pragma unroll
        for (int q = 0; q < 4; ++q) {
            float v0 = acc[m2][0][q] + b1c[0], v1 = acc[m2][1][q] + b1c[1];
            float v2 = acc[m2][2][q] + b1c[2], v3 = acc[m2][3][q] + b1c[3];
            acc[m2][0][q] = v0; acc[m2][1][q] = v1; acc[m2][2][q] = v2; acc[m2][3][q] = v3;
            s[q]  = v0 + v1 + v2 + v3;
            ss[q] = v0*v0 + v1*v1 + v2*v2 + v3*v3;
        }
#pragma unroll
        for (int q = 0; q < 4; ++q) {
#pragma unroll
            for (int d = 1; d < 16; d <<= 1) {
                s[q]  += __shfl_xor(s[q],  d, 16);
                ss[q] += __shfl_xor(ss[q], d, 16);
            }
        }
#pragma unroll
        for (int q = 0; q < 4; ++q) {
            float mu   = s[q] * (1.0f/64.0f);
            float var  = ss[q] * (1.0f/64.0f) - mu*mu;
            float istd = frsq(var + 1e-5f);
            int r = m2*16 + g*4 + q;
#pragma unroll
            for (int t2 = 0; t2 < 4; ++t2) {
                float v = ftanh(fmaf((acc[m2][t2][q] - mu) * istd, lgc[t2], lbc[t2]));
                hb[r*72 + cl + 16*t2] = f16bits(v);
            }
        }
    }
    __syncthreads();

    // ---- enc2 MFMA + relu -> hb ----
    FragH ah[2][4];
#pragma unroll
    for (int m2 = 0; m2 < 2; ++m2)
#pragma unroll
        for (int ks = 0; ks < 4; ++ks)
            ah[m2][ks].uh = *reinterpret_cast<const u16x4v*>(&hb[(m2*16 + cl)*72 + ks*16 + 4*g]);
    f32x4 a2[2][4];
#pragma unroll
    for (int m2 = 0; m2 < 2; ++m2)
#pragma unroll
        for (int ct = 0; ct < 4; ++ct) a2[m2][ct] = vzero;
#pragma unroll
    for (int ct = 0; ct < 4; ++ct)
#pragma unroll
        for (int ks = 0; ks < 4; ++ks) {
            Frag2 bf; bf.u2 = BF2[(8 + ks*4 + ct)*64 + l];
#pragma unroll
            for (int m2 = 0; m2 < 2; ++m2)
                a2[m2][ct] = mfma16(ah[m2][ks].f, bf.f, a2[m2][ct]);
        }
    __syncthreads();
#pragma unroll
    for (int m2 = 0; m2 < 2; ++m2)
#pragma unroll
        for (int q = 0; q < 4; ++q) {
            int r = m2*16 + g*4 + q;
#pragma unroll
            for (int t2 = 0; t2 < 4; ++t2)
                hb[r*72 + cl + 16*t2] = f16bits(fmaxf(a2[m2][t2][q] + b2c[t2], 0.0f));
        }
    __syncthreads();

    // ---- enc3 MFMA -> latent (store out + stage f32 in at) ----
#pragma unroll
    for (int m2 = 0; m2 < 2; ++m2)
#pragma unroll
        for (int ks = 0; ks < 4; ++ks)
            ah[m2][ks].uh = *reinterpret_cast<const u16x4v*>(&hb[(m2*16 + cl)*72 + ks*16 + 4*g]);
#pragma unroll
    for (int m2 = 0; m2 < 2; ++m2) {
        f32x4 a3 = vzero;
#pragma unroll
        for (int ks = 0; ks < 4; ++ks) {
            Frag2 bf; bf.u2 = BF2[(24 + ks)*64 + l];
            a3 = mfma16(ah[m2][ks].f, bf.f, a3);
        }
#pragma unroll
        for (int q = 0; q < 4; ++q) {
            float lv = a3[q] + b3c;
            int r = m2*16 + g*4 + q;
            if (cl < 14)
                out[(long long)8 * N + (rowbase + r) * 14 + cl] = lv;
            at[r*36 + cl] = __builtin_bit_cast(unsigned, lv);
        }
    }
    __syncthreads();

    // ============ T3: dec1+dec2 via dot2 (lanes 0..31; R8-PROVEN path) ============
    if (l < 32) {
        const long long row = rowbase + l;
        float latv[14];
#pragma unroll
        for (int c = 0; c < 14; ++c) latv[c] = __builtin_bit_cast(float, at[l*36 + c]);
        unsigned latp[7];
#pragma unroll
        for (int kk = 0; kk < 7; ++kk) latp[kk] = packrtz(latv[2*kk], latv[2*kk+1]);

        float d1[HD];
#pragma unroll
        for (int j = 0; j < HD; ++j) d1[j] = bd1[j];
#pragma unroll
        for (int kk = 0; kk < 7; ++kk) {
            unsigned x = latp[kk];
            const unsigned* wr = pw + PD1_OFF + kk * HD;
#pragma unroll
            for (int j = 0; j < HD; ++j) d1[j] = dot2(x, wr[j], d1[j]);
        }
#pragma unroll
        for (int j = 0; j < HD; ++j) d1[j] = fmaxf(d1[j], 0.0f);

        unsigned d1p[32];
#pragma unroll
        for (int kk = 0; kk < 32; ++kk) d1p[kk] = packrtz(d1[2*kk], d1[2*kk+1]);
        float c8[8];
#pragma unroll
        for (int j = 0; j < 8; ++j) c8[j] = bd2[j];
#pragma unroll
        for (int kk = 0; kk < 32; ++kk) {
            unsigned x = d1p[kk];
            const unsigned* wr = pw + PD2_OFF + kk * 8;
#pragma unroll
            for (int j = 0; j < 8; ++j) c8[j] = dot2(x, wr[j], c8[j]);
        }
        float* pc = out + row * 8;
        reinterpret_cast<float4*>(pc)[0] =
            make_float4(ftanh(c8[0]), ftanh(c8[1]), ftanh(c8[2]), ftanh(c8[3]));
        reinterpret_cast<float4*>(pc)[1] =
            make_float4(ftanh(c8[4]), ftanh(c8[5]), ftanh(c8[6]), ftanh(c8[7]));
    }
}

extern "C" void kernel_launch(void* const* d_in, const int* in_sizes, int n_in,
                              void* d_out, int out_size, void* d_ws, size_t ws_size,
                              hipStream_t stream)
{
    const float* state = (const float*)d_in[0];
    const float* W1   = (const float*)d_in[1];
    const float* b1   = (const float*)d_in[2];
    const float* lng  = (const float*)d_in[3];
    const float* lnb  = (const float*)d_in[4];
    const float* W2   = (const float*)d_in[5];
    const float* b2   = (const float*)d_in[6];
    const float* W3   = (const float*)d_in[7];
    const float* b3   = (const float*)d_in[8];
    const float* Wd1  = (const float*)d_in[9];
    const float* bd1  = (const float*)d_in[10];
    const float* Wd2  = (const float*)d_in[11];
    const float* bd2  = (const float*)d_in[12];
    const float* Wm   = (const float*)d_in[13];
    const float* bm   = (const float*)d_in[14];
    const float* Wh   = (const float*)d_in[15];
    const float* bh   = (const float*)d_in[16];
    const float* Wc   = (const float*)d_in[17];
    const float* bc   = (const float*)d_in[18];
    const float* psm  = (const float*)d_in[19];
    const float* psh  = (const float*)d_in[20];
    const float* psc  = (const float*)d_in[21];

    unsigned* pw = (unsigned*)d_ws;

    hipLaunchKernelGGL(pack_weights_kernel, dim3((PTOT + 255)/256), dim3(256), 0, stream,
                       W1, W2, W3, Wd1, Wd2, pw);
    hipLaunchKernelGGL(pack_bfrags, dim3((NFRAG*64 + 255)/256), dim3(256), 0, stream,
                       W1, W2, W3, Wd1, Wd2, pw);

    const int N = in_sizes[0] / SD;              // 1048576
    hipLaunchKernelGGL(statenet_hybrid2, dim3(N / 128), dim3(256), 0, stream,
                       state, pw, b1, lng, lnb, b2, b3, bd1, bd2,
                       Wm, bm, Wh, bh, Wc, bc, psm, psh, psc,
                       (float*)d_out, N);
}

// Round 16
// 127.951 us; speedup vs baseline: 2.3446x; 1.2692x over previous
//
#include <hip/hip_runtime.h>

static constexpr int SD = 21, HD = 64, LT = 14;
static constexpr int NFRAG = 36;     // 16x16x16 B-fragments, ws[fid*128 + lane*2 + j]

typedef _Float16       f16x4  __attribute__((ext_vector_type(4)));
typedef float          f32x4  __attribute__((ext_vector_type(4)));
typedef unsigned       u32x2v __attribute__((ext_vector_type(2)));
typedef unsigned short u16x4v __attribute__((ext_vector_type(4)));
typedef __fp16         pk2    __attribute__((ext_vector_type(2)));

__device__ __forceinline__ float frcp(float x){ return __builtin_amdgcn_rcpf(x); }
__device__ __forceinline__ float frsq(float x){ return __builtin_amdgcn_rsqf(x); }

__device__ __forceinline__ unsigned packrtz(float a, float b){
    pk2 h = __builtin_amdgcn_cvt_pkrtz(a, b);
    union { pk2 h; unsigned u; } u; u.h = h; return u.u;
}
__device__ __forceinline__ unsigned short f16bits(float v){
    _Float16 h = (_Float16)v;
    union { _Float16 h; unsigned short s; } u; u.h = h; return u.s;
}
__device__ __forceinline__ float ftanh(float x){
    x = fminf(15.0f, fmaxf(-15.0f, x));
    float e = __expf(2.0f * x);
    return (e - 1.0f) * frcp(e + 1.0f);
}
template<int NN>
__device__ __forceinline__ void softmax_scale(float (&v)[NN], float gate){
    float mx = v[0];
#pragma unroll
    for (int j = 1; j < NN; ++j) mx = fmaxf(mx, v[j]);
    float s = 0.0f;
#pragma unroll
    for (int j = 0; j < NN; ++j){ v[j] = __expf(v[j] - mx); s += v[j]; }
    float r = frcp(s) * gate;
#pragma unroll
    for (int j = 0; j < NN; ++j) v[j] *= r;
}

union Frag2 { u32x2v u2; unsigned u[2]; f16x4 f; };
union FragH { u16x4v uh; f16x4 f; };

__device__ __forceinline__ f32x4 mfma16(f16x4 a, f16x4 b, f32x4 c){
    return __builtin_amdgcn_mfma_f32_16x16x16f16(a, b, c, 0, 0, 0);
}

// ---- B-fragment pack: layout col=l&15, k=4*(l>>4)+r (HW-verified R12/R13/R14) ----
// fid: 0-7 enc1 | 8-23 enc2 | 24-27 enc3 | 28-31 dec1 | 32-35 dec2
__global__ void pack_bfrags(const float* __restrict__ W1, const float* __restrict__ W2,
                            const float* __restrict__ W3, const float* __restrict__ Wd1,
                            const float* __restrict__ Wd2, unsigned* __restrict__ ws)
{
    int t = blockIdx.x * blockDim.x + threadIdx.x;
    if (t >= NFRAG * 64) return;
    int fid = t >> 6, lane = t & 63;
    int g = lane >> 4, c = lane & 15;
    const float* W; int ks16, ct, K, Ncol, ld;
    if (fid < 8)       { W = W1;  ks16 = fid >> 2;    ct = fid & 3;  K = 21; Ncol = 64; ld = 64; }
    else if (fid < 24) { int e = fid - 8;
                         W = W2;  ks16 = e >> 2;      ct = e & 3;    K = 64; Ncol = 64; ld = 64; }
    else if (fid < 28) { W = W3;  ks16 = fid - 24;    ct = 0;        K = 64; Ncol = 14; ld = 14; }
    else if (fid < 32) { W = Wd1; ks16 = 0;           ct = fid - 28; K = 14; Ncol = 64; ld = 64; }
    else               { W = Wd2; ks16 = fid - 32;    ct = 0;        K = 64; Ncol = 8;  ld = 8;  }
    int col = ct*16 + c;
#pragma unroll
    for (int j = 0; j < 2; ++j) {
        int k0 = ks16*16 + g*4 + 2*j;
        float a = (k0     < K && col < Ncol) ? W[k0*ld + col]     : 0.0f;
        float b = (k0 + 1 < K && col < Ncol) ? W[(k0+1)*ld + col] : 0.0f;
        ws[fid*128 + lane*2 + j] = packrtz(a, b);
    }
}

__global__ __launch_bounds__(256) void statenet_mfma3(
    const float* __restrict__ state,
    const unsigned* __restrict__ pw,
    const float* __restrict__ b1,
    const float* __restrict__ lng, const float* __restrict__ lnb,
    const float* __restrict__ b2,  const float* __restrict__ b3,
    const float* __restrict__ bd1, const float* __restrict__ bd2,
    const float* __restrict__ Wm,  const float* __restrict__ bm,
    const float* __restrict__ Wh,  const float* __restrict__ bh,
    const float* __restrict__ Wc,  const float* __restrict__ bc,
    const float* __restrict__ psm, const float* __restrict__ psh,
    const float* __restrict__ psc,
    float* __restrict__ out, int N)
{
    __shared__ __align__(16) unsigned       s_al[4*1152];   // at / latent f16-pairs [32][36]/wave
    __shared__ __align__(16) unsigned short s_hb[4*2304];   // h [32][72] f16 /wave

    const int tid = threadIdx.x;
    const int w  = tid >> 6, l = tid & 63;
    const int cl = l & 15,  g = l >> 4;
    const long long rowbase = (long long)blockIdx.x * 128 + w * 32;

    unsigned*       at = s_al + w * 1152;
    unsigned short* hb = s_hb + w * 2304;

    // ============ T1: heads + attended staging (lanes 0..31; VERIFIED) ============
    if (l < 32) {
        const long long row = rowbase + l;
        float ns[SD];
        {
            const float* p = state + row * SD;
#pragma unroll
            for (int k = 0; k < SD; ++k) ns[k] = p[k];
        }
        ns[0]  *= (1.0f / 3.0f);
        ns[1]  *= (1.0f / 3.0f);
        ns[17] *= 0.5f;
        ns[18] *= 0.25f;
        ns[19]  = fminf(fmaxf(ns[19], 0.0f), 2.0f) * 0.5f;

        float m[13], hv[6], cv[4];
#pragma unroll
        for (int j = 0; j < 13; ++j) m[j]  = bm[j];
#pragma unroll
        for (int j = 0; j < 6;  ++j) hv[j] = bh[j];
#pragma unroll
        for (int j = 0; j < 4;  ++j) cv[j] = bc[j];
#pragma unroll
        for (int k = 0; k < SD; ++k) {
            float x = ns[k];
#pragma unroll
            for (int j = 0; j < 13; ++j) m[j]  = fmaf(x, Wm[k * 13 + j], m[j]);
#pragma unroll
            for (int j = 0; j < 6;  ++j) hv[j] = fmaf(x, Wh[k * 6 + j], hv[j]);
#pragma unroll
            for (int j = 0; j < 4;  ++j) cv[j] = fmaf(x, Wc[k * 4 + j], cv[j]);
        }
        const float gm = 2.0f * frcp(1.0f + __expf(-psm[0]));
        const float gh = 2.0f * frcp(1.0f + __expf(-psh[0]));
        const float gc = 2.0f * frcp(1.0f + __expf(-psc[0]));
        softmax_scale<13>(m,  gm);
        softmax_scale<6 >(hv, gh);
        softmax_scale<4 >(cv, gc);

        {
            float* pm = out + (long long)22 * N + row * 13;
#pragma unroll
            for (int j = 0; j < 13; ++j) pm[j] = m[j];
            float* ph = out + (long long)35 * N + row * 6;
#pragma unroll
            for (int j = 0; j < 3; ++j)
                reinterpret_cast<float2*>(ph)[j] = make_float2(hv[2*j], hv[2*j+1]);
            float* pc = out + (long long)41 * N + row * 4;
            reinterpret_cast<float4*>(pc)[0] = make_float4(cv[0], cv[1], cv[2], cv[3]);
        }

        constexpr int EIDX[SD] = {0,1,2,3,4,4,5,5,5,6,6,6,7,7,8,9,9,10,10,11,12};
        float atv[SD];
#pragma unroll
        for (int k = 0; k < SD; ++k) atv[k] = ns[k] * m[EIDX[k]];
        const int base = l * 36;
#pragma unroll
        for (int kk = 0; kk < 10; ++kk) at[base + kk] = packrtz(atv[2*kk], atv[2*kk+1]);
        at[base + 10] = packrtz(atv[20], 0.0f);
#pragma unroll
        for (int kk = 11; kk < 16; ++kk) at[base + kk] = 0u;
    }
    __syncthreads();

    // ============ MFMA phase ============
    float b1c[4], b2c[4], bd1c[4], lgc[4], lbc[4];
#pragma unroll
    for (int t2 = 0; t2 < 4; ++t2) {
        int c2 = cl + 16*t2;
        b1c[t2] = b1[c2];  b2c[t2] = b2[c2];  bd1c[t2] = bd1[c2];
        lgc[t2] = lng[c2]; lbc[t2] = lnb[c2];
    }
    const float b3c  = (cl < 14) ? b3[cl]  : 0.0f;
    const float bd2c = (cl < 8)  ? bd2[cl] : 0.0f;

    const u32x2v* BF2 = reinterpret_cast<const u32x2v*>(pw);
    const f32x4 vzero = {0.0f, 0.0f, 0.0f, 0.0f};

    // ---- enc1 MFMA + LN + tanh -> hb (VERIFIED) ----
    Frag2 aA[2][2];
#pragma unroll
    for (int m2 = 0; m2 < 2; ++m2)
#pragma unroll
        for (int ks = 0; ks < 2; ++ks)
            aA[m2][ks].u2 = *reinterpret_cast<const u32x2v*>(&at[(m2*16 + cl)*36 + ks*8 + 2*g]);
    f32x4 acc[2][4];
#pragma unroll
    for (int m2 = 0; m2 < 2; ++m2)
#pragma unroll
        for (int ct = 0; ct < 4; ++ct) acc[m2][ct] = vzero;
#pragma unroll
    for (int ct = 0; ct < 4; ++ct)
#pragma unroll
        for (int ks = 0; ks < 2; ++ks) {
            Frag2 bf; bf.u2 = BF2[(ks*4 + ct)*64 + l];
#pragma unroll
            for (int m2 = 0; m2 < 2; ++m2)
                acc[m2][ct] = mfma16(aA[m2][ks].f, bf.f, acc[m2][ct]);
        }
#pragma unroll
    for (int m2 = 0; m2 < 2; ++m2) {
        float s[4], ss[4];
#pragma unroll
        for (int q = 0; q < 4; ++q) {
            float v0 = acc[m2][0][q] + b1c[0], v1 = acc[m2][1][q] + b1c[1];
            float v2 = acc[m2][2][q] + b1c[2], v3 = acc[m2][3][q] + b1c[3];
            acc[m2][0][q] = v0; acc[m2][1][q] = v1; acc[m2][2][q] = v2; acc[m2][3][q] = v3;
            s[q]  = v0 + v1 + v2 + v3;
            ss[q] = v0*v0 + v1*v1 + v2*v2 + v3*v3;
        }
#pragma unroll
        for (int q = 0; q < 4; ++q) {
#pragma unroll
            for (int d = 1; d < 16; d <<= 1) {
                s[q]  += __shfl_xor(s[q],  d, 16);
                ss[q] += __shfl_xor(ss[q], d, 16);
            }
        }
#pragma unroll
        for (int q = 0; q < 4; ++q) {
            float mu   = s[q] * (1.0f/64.0f);
            float var  = ss[q] * (1.0f/64.0f) - mu*mu;
            float istd = frsq(var + 1e-5f);
            int r = m2*16 + g*4 + q;
#pragma unroll
            for (int t2 = 0; t2 < 4; ++t2) {
                float v = ftanh(fmaf((acc[m2][t2][q] - mu) * istd, lgc[t2], lbc[t2]));
                hb[r*72 + cl + 16*t2] = f16bits(v);
            }
        }
    }
    __syncthreads();

    // ---- enc2 MFMA + relu -> hb (VERIFIED) ----
    FragH ah[2][4];
#pragma unroll
    for (int m2 = 0; m2 < 2; ++m2)
#pragma unroll
        for (int ks = 0; ks < 4; ++ks)
            ah[m2][ks].uh = *reinterpret_cast<const u16x4v*>(&hb[(m2*16 + cl)*72 + ks*16 + 4*g]);
    f32x4 a2[2][4];
#pragma unroll
    for (int m2 = 0; m2 < 2; ++m2)
#pragma unroll
        for (int ct = 0; ct < 4; ++ct) a2[m2][ct] = vzero;
#pragma unroll
    for (int ct = 0; ct < 4; ++ct)
#pragma unroll
        for (int ks = 0; ks < 4; ++ks) {
            Frag2 bf; bf.u2 = BF2[(8 + ks*4 + ct)*64 + l];
#pragma unroll
            for (int m2 = 0; m2 < 2; ++m2)
                a2[m2][ct] = mfma16(ah[m2][ks].f, bf.f, a2[m2][ct]);
        }
    __syncthreads();
#pragma unroll
    for (int m2 = 0; m2 < 2; ++m2)
#pragma unroll
        for (int q = 0; q < 4; ++q) {
            int r = m2*16 + g*4 + q;
#pragma unroll
            for (int t2 = 0; t2 < 4; ++t2)
                hb[r*72 + cl + 16*t2] = f16bits(fmaxf(a2[m2][t2][q] + b2c[t2], 0.0f));
        }
    __syncthreads();

    // ---- enc3 MFMA -> latent: store out + stage as f16 PAIRS (T1 format) ----
#pragma unroll
    for (int m2 = 0; m2 < 2; ++m2)
#pragma unroll
        for (int ks = 0; ks < 4; ++ks)
            ah[m2][ks].uh = *reinterpret_cast<const u16x4v*>(&hb[(m2*16 + cl)*72 + ks*16 + 4*g]);
#pragma unroll
    for (int m2 = 0; m2 < 2; ++m2) {
        f32x4 a3 = vzero;
#pragma unroll
        for (int ks = 0; ks < 4; ++ks) {
            Frag2 bf; bf.u2 = BF2[(24 + ks)*64 + l];
            a3 = mfma16(ah[m2][ks].f, bf.f, a3);
        }
#pragma unroll
        for (int q = 0; q < 4; ++q) {
            float lv = a3[q] + b3c;                 // pad cols 14/15 = 0
            int r = m2*16 + g*4 + q;
            if (cl < 14)
                out[(long long)8 * N + (rowbase + r) * 14 + cl] = lv;
            // pair with column-partner lane (cl^1) -> f16-pair staging, T1 format
            float pv = __shfl_xor(lv, 1);
            if ((cl & 1) == 0)
                at[r*36 + (cl >> 1)] = packrtz(lv, pv);   // pairs 0..7 (k=0..15; 14,15=0)
        }
    }
    __syncthreads();

    // ---- dec1 MFMA + relu -> hb (A-read = enc1-verified pattern, ks=0 only) ----
    Frag2 aD[2];
#pragma unroll
    for (int m2 = 0; m2 < 2; ++m2)
        aD[m2].u2 = *reinterpret_cast<const u32x2v*>(&at[(m2*16 + cl)*36 + 2*g]);
    f32x4 ad[2][4];
#pragma unroll
    for (int m2 = 0; m2 < 2; ++m2)
#pragma unroll
        for (int ct = 0; ct < 4; ++ct) ad[m2][ct] = vzero;
#pragma unroll
    for (int ct = 0; ct < 4; ++ct) {
        Frag2 bf; bf.u2 = BF2[(28 + ct)*64 + l];
#pragma unroll
        for (int m2 = 0; m2 < 2; ++m2)
            ad[m2][ct] = mfma16(aD[m2].f, bf.f, ad[m2][ct]);
    }
#pragma unroll
    for (int m2 = 0; m2 < 2; ++m2)
#pragma unroll
        for (int q = 0; q < 4; ++q) {
            int r = m2*16 + g*4 + q;
#pragma unroll
            for (int t2 = 0; t2 < 4; ++t2)
                hb[r*72 + cl + 16*t2] = f16bits(fmaxf(ad[m2][t2][q] + bd1c[t2], 0.0f));
        }
    __syncthreads();

    // ---- dec2 MFMA (VERIFIED R14) -> tanh -> corrections ----
#pragma unroll
    for (int m2 = 0; m2 < 2; ++m2)
#pragma unroll
        for (int ks = 0; ks < 4; ++ks)
            ah[m2][ks].uh = *reinterpret_cast<const u16x4v*>(&hb[(m2*16 + cl)*72 + ks*16 + 4*g]);
#pragma unroll
    for (int m2 = 0; m2 < 2; ++m2) {
        f32x4 a5 = vzero;
#pragma unroll
        for (int ks = 0; ks < 4; ++ks) {
            Frag2 bf; bf.u2 = BF2[(32 + ks)*64 + l];
            a5 = mfma16(ah[m2][ks].f, bf.f, a5);
        }
#pragma unroll
        for (int q = 0; q < 4; ++q) {
            if (cl < 8)
                out[(rowbase + m2*16 + g*4 + q) * 8 + cl] = ftanh(a5[q] + bd2c);
        }
    }
}

extern "C" void kernel_launch(void* const* d_in, const int* in_sizes, int n_in,
                              void* d_out, int out_size, void* d_ws, size_t ws_size,
                              hipStream_t stream)
{
    const float* state = (const float*)d_in[0];
    const float* W1   = (const float*)d_in[1];
    const float* b1   = (const float*)d_in[2];
    const float* lng  = (const float*)d_in[3];
    const float* lnb  = (const float*)d_in[4];
    const float* W2   = (const float*)d_in[5];
    const float* b2   = (const float*)d_in[6];
    const float* W3   = (const float*)d_in[7];
    const float* b3   = (const float*)d_in[8];
    const float* Wd1  = (const float*)d_in[9];
    const float* bd1  = (const float*)d_in[10];
    const float* Wd2  = (const float*)d_in[11];
    const float* bd2  = (const float*)d_in[12];
    const float* Wm   = (const float*)d_in[13];
    const float* bm   = (const float*)d_in[14];
    const float* Wh   = (const float*)d_in[15];
    const float* bh   = (const float*)d_in[16];
    const float* Wc   = (const float*)d_in[17];
    const float* bc   = (const float*)d_in[18];
    const float* psm  = (const float*)d_in[19];
    const float* psh  = (const float*)d_in[20];
    const float* psc  = (const float*)d_in[21];

    unsigned* pw = (unsigned*)d_ws;

    hipLaunchKernelGGL(pack_bfrags, dim3((NFRAG*64 + 255)/256), dim3(256), 0, stream,
                       W1, W2, W3, Wd1, Wd2, pw);

    const int N = in_sizes[0] / SD;              // 1048576
    hipLaunchKernelGGL(statenet_mfma3, dim3(N / 128), dim3(256), 0, stream,
                       state, pw, b1, lng, lnb, b2, b3, bd1, bd2,
                       Wm, bm, Wh, bh, Wc, bc, psm, psh, psc,
                       (float*)d_out, N);
}

// Round 17
// 127.512 us; speedup vs baseline: 2.3527x; 1.0034x over previous
//
#include <hip/hip_runtime.h>

static constexpr int SD = 21, HD = 64, LT = 14;
static constexpr int NFRAG = 36;     // 16x16x16 B-fragments, ws[fid*128 + lane*2 + j]

typedef _Float16       f16x4  __attribute__((ext_vector_type(4)));
typedef float          f32x4  __attribute__((ext_vector_type(4)));
typedef unsigned       u32x2v __attribute__((ext_vector_type(2)));
typedef unsigned short u16x4v __attribute__((ext_vector_type(4)));
typedef __fp16         pk2    __attribute__((ext_vector_type(2)));

__device__ __forceinline__ float frcp(float x){ return __builtin_amdgcn_rcpf(x); }
__device__ __forceinline__ float frsq(float x){ return __builtin_amdgcn_rsqf(x); }

__device__ __forceinline__ unsigned packrtz(float a, float b){
    pk2 h = __builtin_amdgcn_cvt_pkrtz(a, b);
    union { pk2 h; unsigned u; } u; u.h = h; return u.u;
}
__device__ __forceinline__ unsigned short f16bits(float v){
    _Float16 h = (_Float16)v;
    union { _Float16 h; unsigned short s; } u; u.h = h; return u.s;
}
__device__ __forceinline__ float ftanh(float x){
    x = fminf(15.0f, fmaxf(-15.0f, x));
    float e = __expf(2.0f * x);
    return (e - 1.0f) * frcp(e + 1.0f);
}
template<int NN>
__device__ __forceinline__ void softmax_scale(float (&v)[NN], float gate){
    float mx = v[0];
#pragma unroll
    for (int j = 1; j < NN; ++j) mx = fmaxf(mx, v[j]);
    float s = 0.0f;
#pragma unroll
    for (int j = 0; j < NN; ++j){ v[j] = __expf(v[j] - mx); s += v[j]; }
    float r = frcp(s) * gate;
#pragma unroll
    for (int j = 0; j < NN; ++j) v[j] *= r;
}

union Frag2 { u32x2v u2; unsigned u[2]; f16x4 f; };
union FragH { u16x4v uh; f16x4 f; };

__device__ __forceinline__ f32x4 mfma16(f16x4 a, f16x4 b, f32x4 c){
    return __builtin_amdgcn_mfma_f32_16x16x16f16(a, b, c, 0, 0, 0);
}

// ---- B-fragment pack: layout col=l&15, k=4*(l>>4)+r (HW-verified R12/R13/R14) ----
// fid: 0-7 enc1 | 8-23 enc2 | 24-27 enc3 | 28-31 dec1 | 32-35 dec2
__global__ void pack_bfrags(const float* __restrict__ W1, const float* __restrict__ W2,
                            const float* __restrict__ W3, const float* __restrict__ Wd1,
                            const float* __restrict__ Wd2, unsigned* __restrict__ ws)
{
    int t = blockIdx.x * blockDim.x + threadIdx.x;
    if (t >= NFRAG * 64) return;
    int fid = t >> 6, lane = t & 63;
    int g = lane >> 4, c = lane & 15;
    const float* W; int ks16, ct, K, Ncol, ld;
    if (fid < 8)       { W = W1;  ks16 = fid >> 2;    ct = fid & 3;  K = 21; Ncol = 64; ld = 64; }
    else if (fid < 24) { int e = fid - 8;
                         W = W2;  ks16 = e >> 2;      ct = e & 3;    K = 64; Ncol = 64; ld = 64; }
    else if (fid < 28) { W = W3;  ks16 = fid - 24;    ct = 0;        K = 64; Ncol = 14; ld = 14; }
    else if (fid < 32) { W = Wd1; ks16 = 0;           ct = fid - 28; K = 14; Ncol = 64; ld = 64; }
    else               { W = Wd2; ks16 = fid - 32;    ct = 0;        K = 64; Ncol = 8;  ld = 8;  }
    int col = ct*16 + c;
#pragma unroll
    for (int j = 0; j < 2; ++j) {
        int k0 = ks16*16 + g*4 + 2*j;
        float a = (k0     < K && col < Ncol) ? W[k0*ld + col]     : 0.0f;
        float b = (k0 + 1 < K && col < Ncol) ? W[(k0+1)*ld + col] : 0.0f;
        ws[fid*128 + lane*2 + j] = packrtz(a, b);
    }
}

__global__ __launch_bounds__(256) void statenet_mfma4(
    const float* __restrict__ state,
    const unsigned* __restrict__ pw,
    const float* __restrict__ b1,
    const float* __restrict__ lng, const float* __restrict__ lnb,
    const float* __restrict__ b2,  const float* __restrict__ b3,
    const float* __restrict__ bd1, const float* __restrict__ bd2,
    const float* __restrict__ Wm,  const float* __restrict__ bm,
    const float* __restrict__ Wh,  const float* __restrict__ bh,
    const float* __restrict__ Wc,  const float* __restrict__ bc,
    const float* __restrict__ psm, const float* __restrict__ psh,
    const float* __restrict__ psc,
    float* __restrict__ out, int N)
{
    // OVERLAY: one 4608 B region per wave serves as BOTH
    //   at: [32][36] u32 (f16-pair staging / latent)   and
    //   hb: [32][72] f16 (hidden activations)
    // Never live simultaneously; every region-role transition is separated by
    // __syncthreads() so the compiler cannot reorder cross-type LDS accesses.
    __shared__ __align__(16) unsigned s_buf[4*1152];     // 18432 B -> 8 blocks/CU

    const int tid = threadIdx.x;
    const int w  = tid >> 6, l = tid & 63;
    const int cl = l & 15,  g = l >> 4;
    const long long rowbase = (long long)blockIdx.x * 128 + w * 32;

    unsigned*       at = s_buf + w * 1152;
    unsigned short* hb = reinterpret_cast<unsigned short*>(s_buf) + w * 2304;

    // ============ T1: heads + attended staging (lanes 0..31; VERIFIED) ============
    if (l < 32) {
        const long long row = rowbase + l;
        float ns[SD];
        {
            const float* p = state + row * SD;
#pragma unroll
        for (int k = 0; k < SD; ++k) ns[k] = p[k];
        }
        ns[0]  *= (1.0f / 3.0f);
        ns[1]  *= (1.0f / 3.0f);
        ns[17] *= 0.5f;
        ns[18] *= 0.25f;
        ns[19]  = fminf(fmaxf(ns[19], 0.0f), 2.0f) * 0.5f;

        float m[13], hv[6], cv[4];
#pragma unroll
        for (int j = 0; j < 13; ++j) m[j]  = bm[j];
#pragma unroll
        for (int j = 0; j < 6;  ++j) hv[j] = bh[j];
#pragma unroll
        for (int j = 0; j < 4;  ++j) cv[j] = bc[j];
#pragma unroll
        for (int k = 0; k < SD; ++k) {
            float x = ns[k];
#pragma unroll
            for (int j = 0; j < 13; ++j) m[j]  = fmaf(x, Wm[k * 13 + j], m[j]);
#pragma unroll
            for (int j = 0; j < 6;  ++j) hv[j] = fmaf(x, Wh[k * 6 + j], hv[j]);
#pragma unroll
            for (int j = 0; j < 4;  ++j) cv[j] = fmaf(x, Wc[k * 4 + j], cv[j]);
        }
        const float gm = 2.0f * frcp(1.0f + __expf(-psm[0]));
        const float gh = 2.0f * frcp(1.0f + __expf(-psh[0]));
        const float gc = 2.0f * frcp(1.0f + __expf(-psc[0]));
        softmax_scale<13>(m,  gm);
        softmax_scale<6 >(hv, gh);
        softmax_scale<4 >(cv, gc);

        {
            float* pm = out + (long long)22 * N + row * 13;
#pragma unroll
            for (int j = 0; j < 13; ++j) pm[j] = m[j];
            float* ph = out + (long long)35 * N + row * 6;
#pragma unroll
            for (int j = 0; j < 3; ++j)
                reinterpret_cast<float2*>(ph)[j] = make_float2(hv[2*j], hv[2*j+1]);
            float* pc = out + (long long)41 * N + row * 4;
            reinterpret_cast<float4*>(pc)[0] = make_float4(cv[0], cv[1], cv[2], cv[3]);
        }

        constexpr int EIDX[SD] = {0,1,2,3,4,4,5,5,5,6,6,6,7,7,8,9,9,10,10,11,12};
        float atv[SD];
#pragma unroll
        for (int k = 0; k < SD; ++k) atv[k] = ns[k] * m[EIDX[k]];
        const int base = l * 36;
#pragma unroll
        for (int kk = 0; kk < 10; ++kk) at[base + kk] = packrtz(atv[2*kk], atv[2*kk+1]);
        at[base + 10] = packrtz(atv[20], 0.0f);
#pragma unroll
        for (int kk = 11; kk < 16; ++kk) at[base + kk] = 0u;
    }
    __syncthreads();                                   // B1: at ready

    // ============ MFMA phase ============
    float b1c[4], b2c[4], bd1c[4], lgc[4], lbc[4];
#pragma unroll
    for (int t2 = 0; t2 < 4; ++t2) {
        int c2 = cl + 16*t2;
        b1c[t2] = b1[c2];  b2c[t2] = b2[c2];  bd1c[t2] = bd1[c2];
        lgc[t2] = lng[c2]; lbc[t2] = lnb[c2];
    }
    const float b3c  = (cl < 14) ? b3[cl]  : 0.0f;
    const float bd2c = (cl < 8)  ? bd2[cl] : 0.0f;

    const u32x2v* BF2 = reinterpret_cast<const u32x2v*>(pw);
    const f32x4 vzero = {0.0f, 0.0f, 0.0f, 0.0f};

    // ---- enc1: read at -> regs ----
    Frag2 aA[2][2];
#pragma unroll
    for (int m2 = 0; m2 < 2; ++m2)
#pragma unroll
        for (int ks = 0; ks < 2; ++ks)
            aA[m2][ks].u2 = *reinterpret_cast<const u32x2v*>(&at[(m2*16 + cl)*36 + ks*8 + 2*g]);
    __syncthreads();                                   // B2: at dead, region may become hb

    f32x4 acc[2][4];
#pragma unroll
    for (int m2 = 0; m2 < 2; ++m2)
#pragma unroll
        for (int ct = 0; ct < 4; ++ct) acc[m2][ct] = vzero;
#pragma unroll
    for (int ct = 0; ct < 4; ++ct)
#pragma unroll
        for (int ks = 0; ks < 2; ++ks) {
            Frag2 bf; bf.u2 = BF2[(ks*4 + ct)*64 + l];
#pragma unroll
            for (int m2 = 0; m2 < 2; ++m2)
                acc[m2][ct] = mfma16(aA[m2][ks].f, bf.f, acc[m2][ct]);
        }
    // LN + tanh -> hb (VERIFIED)
#pragma unroll
    for (int m2 = 0; m2 < 2; ++m2) {
        float s[4], ss[4];
#pragma unroll
        for (int q = 0; q < 4; ++q) {
            float v0 = acc[m2][0][q] + b1c[0], v1 = acc[m2][1][q] + b1c[1];
            float v2 = acc[m2][2][q] + b1c[2], v3 = acc[m2][3][q] + b1c[3];
            acc[m2][0][q] = v0; acc[m2][1][q] = v1; acc[m2][2][q] = v2; acc[m2][3][q] = v3;
            s[q]  = v0 + v1 + v2 + v3;
            ss[q] = v0*v0 + v1*v1 + v2*v2 + v3*v3;
        }
#pragma unroll
        for (int q = 0; q < 4; ++q) {
#pragma unroll
            for (int d = 1; d < 16; d <<= 1) {
                s[q]  += __shfl_xor(s[q],  d, 16);
                ss[q] += __shfl_xor(ss[q], d, 16);
            }
        }
#pragma unroll
        for (int q = 0; q < 4; ++q) {
            float mu   = s[q] * (1.0f/64.0f);
            float var  = ss[q] * (1.0f/64.0f) - mu*mu;
            float istd = frsq(var + 1e-5f);
            int r = m2*16 + g*4 + q;
#pragma unroll
            for (int t2 = 0; t2 < 4; ++t2) {
                float v = ftanh(fmaf((acc[m2][t2][q] - mu) * istd, lgc[t2], lbc[t2]));
                hb[r*72 + cl + 16*t2] = f16bits(v);
            }
        }
    }
    __syncthreads();                                   // B3: hb(h1) ready

    // ---- enc2 (VERIFIED) ----
    FragH ah[2][4];
#pragma unroll
    for (int m2 = 0; m2 < 2; ++m2)
#pragma unroll
        for (int ks = 0; ks < 4; ++ks)
            ah[m2][ks].uh = *reinterpret_cast<const u16x4v*>(&hb[(m2*16 + cl)*72 + ks*16 + 4*g]);
    f32x4 a2[2][4];
#pragma unroll
    for (int m2 = 0; m2 < 2; ++m2)
#pragma unroll
        for (int ct = 0; ct < 4; ++ct) a2[m2][ct] = vzero;
#pragma unroll
    for (int ct = 0; ct < 4; ++ct)
#pragma unroll
        for (int ks = 0; ks < 4; ++ks) {
            Frag2 bf; bf.u2 = BF2[(8 + ks*4 + ct)*64 + l];
#pragma unroll
            for (int m2 = 0; m2 < 2; ++m2)
                a2[m2][ct] = mfma16(ah[m2][ks].f, bf.f, a2[m2][ct]);
        }
    __syncthreads();                                   // B4: h1 dead
#pragma unroll
    for (int m2 = 0; m2 < 2; ++m2)
#pragma unroll
        for (int q = 0; q < 4; ++q) {
            int r = m2*16 + g*4 + q;
#pragma unroll
            for (int t2 = 0; t2 < 4; ++t2)
                hb[r*72 + cl + 16*t2] = f16bits(fmaxf(a2[m2][t2][q] + b2c[t2], 0.0f));
        }
    __syncthreads();                                   // B5: hb(h2) ready

    // ---- enc3 (VERIFIED): read h2 -> regs ----
#pragma unroll
    for (int m2 = 0; m2 < 2; ++m2)
#pragma unroll
        for (int ks = 0; ks < 4; ++ks)
            ah[m2][ks].uh = *reinterpret_cast<const u16x4v*>(&hb[(m2*16 + cl)*72 + ks*16 + 4*g]);
    __syncthreads();                                   // B6: h2 dead, region may become at(latent)
#pragma unroll
    for (int m2 = 0; m2 < 2; ++m2) {
        f32x4 a3 = vzero;
#pragma unroll
        for (int ks = 0; ks < 4; ++ks) {
            Frag2 bf; bf.u2 = BF2[(24 + ks)*64 + l];
            a3 = mfma16(ah[m2][ks].f, bf.f, a3);
        }
#pragma unroll
        for (int q = 0; q < 4; ++q) {
            float lv = a3[q] + b3c;                 // pad cols 14/15 = 0
            int r = m2*16 + g*4 + q;
            if (cl < 14)
                out[(long long)8 * N + (rowbase + r) * 14 + cl] = lv;
            // pair with column-partner lane (cl^1) -> f16-pair staging (VERIFIED R16)
            float pv = __shfl_xor(lv, 1);
            if ((cl & 1) == 0)
                at[r*36 + (cl >> 1)] = packrtz(lv, pv);
        }
    }
    __syncthreads();                                   // B7: at(latent) ready

    // ---- dec1 (VERIFIED R16): read latent -> regs ----
    Frag2 aD[2];
#pragma unroll
    for (int m2 = 0; m2 < 2; ++m2)
        aD[m2].u2 = *reinterpret_cast<const u32x2v*>(&at[(m2*16 + cl)*36 + 2*g]);
    __syncthreads();                                   // B8: latent dead, region may become hb
    f32x4 ad[2][4];
#pragma unroll
    for (int m2 = 0; m2 < 2; ++m2)
#pragma unroll
        for (int ct = 0; ct < 4; ++ct) ad[m2][ct] = vzero;
#pragma unroll
    for (int ct = 0; ct < 4; ++ct) {
        Frag2 bf; bf.u2 = BF2[(28 + ct)*64 + l];
#pragma unroll
        for (int m2 = 0; m2 < 2; ++m2)
            ad[m2][ct] = mfma16(aD[m2].f, bf.f, ad[m2][ct]);
    }
#pragma unroll
    for (int m2 = 0; m2 < 2; ++m2)
#pragma unroll
        for (int q = 0; q < 4; ++q) {
            int r = m2*16 + g*4 + q;
#pragma unroll
            for (int t2 = 0; t2 < 4; ++t2)
                hb[r*72 + cl + 16*t2] = f16bits(fmaxf(ad[m2][t2][q] + bd1c[t2], 0.0f));
        }
    __syncthreads();                                   // B9: hb(d1) ready

    // ---- dec2 (VERIFIED R14) -> tanh -> corrections ----
#pragma unroll
    for (int m2 = 0; m2 < 2; ++m2)
#pragma unroll
        for (int ks = 0; ks < 4; ++ks)
            ah[m2][ks].uh = *reinterpret_cast<const u16x4v*>(&hb[(m2*16 + cl)*72 + ks*16 + 4*g]);
#pragma unroll
    for (int m2 = 0; m2 < 2; ++m2) {
        f32x4 a5 = vzero;
#pragma unroll
        for (int ks = 0; ks < 4; ++ks) {
            Frag2 bf; bf.u2 = BF2[(32 + ks)*64 + l];
            a5 = mfma16(ah[m2][ks].f, bf.f, a5);
        }
#pragma unroll
        for (int q = 0; q < 4; ++q) {
            if (cl < 8)
                out[(rowbase + m2*16 + g*4 + q) * 8 + cl] = ftanh(a5[q] + bd2c);
        }
    }
}

extern "C" void kernel_launch(void* const* d_in, const int* in_sizes, int n_in,
                              void* d_out, int out_size, void* d_ws, size_t ws_size,
                              hipStream_t stream)
{
    const float* state = (const float*)d_in[0];
    const float* W1   = (const float*)d_in[1];
    const float* b1   = (const float*)d_in[2];
    const float* lng  = (const float*)d_in[3];
    const float* lnb  = (const float*)d_in[4];
    const float* W2   = (const float*)d_in[5];
    const float* b2   = (const float*)d_in[6];
    const float* W3   = (const float*)d_in[7];
    const float* b3   = (const float*)d_in[8];
    const float* Wd1  = (const float*)d_in[9];
    const float* bd1  = (const float*)d_in[10];
    const float* Wd2  = (const float*)d_in[11];
    const float* bd2  = (const float*)d_in[12];
    const float* Wm   = (const float*)d_in[13];
    const float* bm   = (const float*)d_in[14];
    const float* Wh   = (const float*)d_in[15];
    const float* bh   = (const float*)d_in[16];
    const float* Wc   = (const float*)d_in[17];
    const float* bc   = (const float*)d_in[18];
    const float* psm  = (const float*)d_in[19];
    const float* psh  = (const float*)d_in[20];
    const float* psc  = (const float*)d_in[21];

    unsigned* pw = (unsigned*)d_ws;

    hipLaunchKernelGGL(pack_bfrags, dim3((NFRAG*64 + 255)/256), dim3(256), 0, stream,
                       W1, W2, W3, Wd1, Wd2, pw);

    const int N = in_sizes[0] / SD;              // 1048576
    hipLaunchKernelGGL(statenet_mfma4, dim3(N / 128), dim3(256), 0, stream,
                       state, pw, b1, lng, lnb, b2, b3, bd1, bd2,
                       Wm, bm, Wh, bh, Wc, bc, psm, psh, psc,
                       (float*)d_out, N);
}